// Round 14
// baseline (375.528 us; speedup 1.0000x reference)
//
#include <hip/hip_runtime.h>
#include <hip/hip_bf16.h>

#define B_N 8192
#define C_DIM 512
#define NT 64            // 128-wide tiles per dimension
#define NTRI 2080        // NT*(NT+1)/2 upper-triangle tiles
#define TGKEY 0xBDC0u    // negkey(bf16 0.09375): conservative top-64 pre-threshold
#define NCAP 256         // negative-candidate cap per row (mean ~138, +10 sigma safe)
#define PCAP 192         // positive (same-class) cap per row (class size ~82)

typedef __attribute__((ext_vector_type(4))) float f32x4;
typedef __attribute__((ext_vector_type(8))) __bf16 bf16x8;
typedef __attribute__((address_space(3))) unsigned int lds_u32;
typedef const __attribute__((address_space(1))) unsigned int glb_u32;

__device__ __forceinline__ void gl_lds16(const unsigned short* g, unsigned short* l) {
    __builtin_amdgcn_global_load_lds((glb_u32*)g, (lds_u32*)l, 16, 0, 0);
}

__device__ __forceinline__ unsigned short f2bf(float f) {
    unsigned int u = __float_as_uint(f);
    u += 0x7FFFu + ((u >> 16) & 1u);          // RNE
    return (unsigned short)(u >> 16);
}
__device__ __forceinline__ float bf2f(unsigned int s) {
    return __uint_as_float(s << 16);
}
// order-preserving key: float order -> unsigned ascending. key 0 impossible for finite sims.
__device__ __forceinline__ unsigned negkey(unsigned ub) {
    return (ub & 0x8000u) ? ((~ub) & 0xFFFFu) : (ub | 0x8000u);
}
__device__ __forceinline__ unsigned unkey(unsigned k) {
    return (k & 0x8000u) ? (k ^ 0x8000u) : ((~k) & 0xFFFFu);
}

// ---- zero per-row candidate counters ----
__global__ void zero_cnt(unsigned* __restrict__ ncnt, unsigned* __restrict__ pcnt) {
    const int i = blockIdx.x * 256 + threadIdx.x;     // grid 32 x 256 = 8192
    ncnt[i] = 0u; pcnt[i] = 0u;
}

// ---- detect int64-vs-int32 target layout, emit class bytes ----
__global__ void prep_tgt(const unsigned int* __restrict__ t, unsigned char* __restrict__ tgb) {
    __shared__ int bad;
    if (threadIdx.x == 0) bad = 0;
    __syncthreads();
    int local = 0;
    for (int k = (int)threadIdx.x; k < 4096; k += 256)   // first 32KB only: safe for both layouts
        if (t[2 * k + 1] != 0u) local = 1;
    if (local) atomicOr(&bad, 1);
    __syncthreads();
    const int is64 = (bad == 0);
    for (int j = (int)threadIdx.x; j < B_N; j += 256)
        tgb[j] = (unsigned char)(is64 ? t[2 * j] : t[j]);
}

// ---- L2 normalize rows, emit bf16 ----
__global__ __launch_bounds__(256) void normalize_k(const float* __restrict__ x,
                                                   unsigned short* __restrict__ nf) {
    const int wid = threadIdx.x >> 6, lane = threadIdx.x & 63;
    const size_t row = (size_t)blockIdx.x * 4 + wid;
    const float4* xr = (const float4*)(x + row * C_DIM) + lane * 2;
    float4 a = xr[0], b = xr[1];
    float ss = a.x * a.x + a.y * a.y + a.z * a.z + a.w * a.w +
               b.x * b.x + b.y * b.y + b.z * b.z + b.w * b.w;
#pragma unroll
    for (int m = 1; m < 64; m <<= 1) ss += __shfl_xor(ss, m);
    float sc = 1.0f / fmaxf(sqrtf(ss), 1e-12f);
    union { unsigned short s[8]; int4 v; } o;
    o.s[0] = f2bf(a.x * sc); o.s[1] = f2bf(a.y * sc);
    o.s[2] = f2bf(a.z * sc); o.s[3] = f2bf(a.w * sc);
    o.s[4] = f2bf(b.x * sc); o.s[5] = f2bf(b.y * sc);
    o.s[6] = f2bf(b.z * sc); o.s[7] = f2bf(b.w * sc);
    *(int4*)(nf + row * C_DIM + lane * 8) = o.v;
}

// ---- triangular 128x128-tile GEMM; epilogue emits candidates only (no sim matrix) ----
__global__ __launch_bounds__(256) void gemm_cand(const unsigned short* __restrict__ nf,
                                                 const unsigned char* __restrict__ tgb,
                                                 unsigned short* __restrict__ ncand,
                                                 unsigned* __restrict__ ncnt,
                                                 unsigned short* __restrict__ pcand,
                                                 unsigned* __restrict__ pcnt) {
    __shared__ unsigned short smem[2 * 8192];           // As | Bs, 32 KB
    unsigned short* As = smem;
    unsigned short* Bs = smem + 8192;
    const int idp = (NTRI - 1) - (int)blockIdx.x;       // row-major triangle order
    int u = (int)((sqrtf(8.0f * (float)idp + 1.0f) - 1.0f) * 0.5f);
    while (u * (u + 1) / 2 > idp) --u;
    while ((u + 1) * (u + 2) / 2 <= idp) ++u;
    const int v = idp - u * (u + 1) / 2;
    const int tI = (NT - 1) - u;
    const int tJ = (NT - 1) - v;

    const int tid = threadIdx.x;
    const int wid = tid >> 6, lane = tid & 63;
    const int wm = wid >> 1, wn = wid & 1;
    const int gr = tI * 128;
    const int gc = tJ * 128;
    f32x4 zero = {0.f, 0.f, 0.f, 0.f};
    f32x4 acc[4][4];
#pragma unroll
    for (int m = 0; m < 4; ++m)
#pragma unroll
        for (int n = 0; n < 4; ++n) acc[m][n] = zero;

    const int lr = lane >> 3, lcb = lane & 7;

    for (int k0 = 0; k0 < C_DIM; k0 += 64) {
#pragma unroll
        for (int i = 0; i < 4; ++i) {
            const int chunk = wid * 4 + i;
            const int r = chunk * 8 + lr;
            const int sc = (lcb ^ (r & 7)) << 3;        // inverse-swizzled source col
            gl_lds16(nf + (size_t)(gr + r) * C_DIM + k0 + sc, As + chunk * 512);
            gl_lds16(nf + (size_t)(gc + r) * C_DIM + k0 + sc, Bs + chunk * 512);
        }
        __syncthreads();
#pragma unroll
        for (int kk = 0; kk < 2; ++kk) {
            const int krow = kk * 32 + (lane >> 4) * 8;
            bf16x8 a[4], b[4];
#pragma unroll
            for (int m = 0; m < 4; ++m) {
                const int R = wm * 64 + m * 16 + (lane & 15);
                a[m] = *(const bf16x8*)&As[R * 64 + (krow ^ ((R & 7) << 3))];
            }
#pragma unroll
            for (int n = 0; n < 4; ++n) {
                const int R = wn * 64 + n * 16 + (lane & 15);
                b[n] = *(const bf16x8*)&Bs[R * 64 + (krow ^ ((R & 7) << 3))];
            }
#pragma unroll
            for (int m = 0; m < 4; ++m)
#pragma unroll
                for (int n = 0; n < 4; ++n)
                    acc[m][n] = __builtin_amdgcn_mfma_f32_16x16x32_bf16(a[m], b[n], acc[m][n], 0, 0, 0);
        }
        __syncthreads();
    }

    // epilogue: per-element class compare + candidate append (no tile write)
    const int fr = (lane >> 4) << 2;                     // fragment row base
    const int fc = lane & 15;                            // fragment col
    const bool mirror = (tJ > tI);
    unsigned char cc[4], rc[4][4];
#pragma unroll
    for (int n = 0; n < 4; ++n) cc[n] = tgb[gc + wn * 64 + n * 16 + fc];
#pragma unroll
    for (int m = 0; m < 4; ++m)
#pragma unroll
        for (int j = 0; j < 4; ++j) rc[m][j] = tgb[gr + wm * 64 + m * 16 + fr + j];

#pragma unroll
    for (int m = 0; m < 4; ++m)
#pragma unroll
        for (int n = 0; n < 4; ++n) {
            const int c = gc + wn * 64 + n * 16 + fc;
#pragma unroll
            for (int j = 0; j < 4; ++j) {
                const int r = gr + wm * 64 + m * 16 + fr + j;
                const unsigned key = negkey(f2bf(acc[m][n][j]));
                if (rc[m][j] == cc[n]) {                 // same class -> positive cand
                    unsigned s1 = atomicAdd(&pcnt[r], 1u);
                    if (s1 < PCAP) pcand[(size_t)r * PCAP + s1] = (unsigned short)key;
                    if (mirror) {
                        unsigned s2 = atomicAdd(&pcnt[c], 1u);
                        if (s2 < PCAP) pcand[(size_t)c * PCAP + s2] = (unsigned short)key;
                    }
                } else if (key > TGKEY) {                // negative candidate
                    unsigned s1 = atomicAdd(&ncnt[r], 1u);
                    if (s1 < NCAP) ncand[(size_t)r * NCAP + s1] = (unsigned short)key;
                    if (mirror) {
                        unsigned s2 = atomicAdd(&ncnt[c], 1u);
                        if (s2 < NCAP) ncand[(size_t)c * NCAP + s2] = (unsigned short)key;
                    }
                }
            }
        }
}

// fallback helper: recompute one sim key from nf (exact, self-consistent per row)
__device__ unsigned dotkey(const unsigned short* __restrict__ a,
                           const unsigned short* __restrict__ b) {
    float s = 0.f;
    for (int d = 0; d < C_DIM; d += 8) {
        float p = 0.f;
#pragma unroll
        for (int e = 0; e < 8; ++e)
            p += bf2f(a[d + e]) * bf2f(b[d + e]);
        s += p;
    }
    return negkey(f2bf(s));
}

// ---- wave-per-row selection + loss: no LDS, no barriers ----
__global__ __launch_bounds__(256) void select_loss(
        const unsigned short* __restrict__ ncand, const unsigned* __restrict__ ncnt,
        const unsigned short* __restrict__ pcand, const unsigned* __restrict__ pcnt,
        const unsigned char* __restrict__ tgb, const unsigned short* __restrict__ nf,
        float* __restrict__ out) {
    const int wid = threadIdx.x >> 6, lane = threadIdx.x & 63;
    const int row = blockIdx.x * 4 + wid;
    const int nc = (int)ncnt[row], pc = (int)pcnt[row];

    if (nc >= 64 && nc <= NCAP && pc <= PCAP) {
        // ---- fast path ----
        ushort4 nk = *(const ushort4*)&ncand[(size_t)row * NCAP + lane * 4];
        unsigned cand[4] = {nk.x, nk.y, nk.z, nk.w};
#pragma unroll
        for (int j = 0; j < 4; ++j)
            if (lane * 4 + j >= nc) cand[j] = 0;
        // 16-step bisection: exact 64th-largest key among all row keys > TGKEY
        unsigned cur = 0;
#pragma unroll
        for (int bit = 15; bit >= 0; --bit) {
            unsigned trial = cur | (1u << bit);
            int c = (cand[0] >= trial) + (cand[1] >= trial) +
                    (cand[2] >= trial) + (cand[3] >= trial);
#pragma unroll
            for (int o = 1; o < 64; o <<= 1) c += __shfl_xor(c, o);
            if (c >= 64) cur = trial;
        }
        int r = (cand[0] > cur) + (cand[1] > cur) + (cand[2] > cur) + (cand[3] > cur);
        float f = 0.f;
#pragma unroll
        for (int j = 0; j < 4; ++j)
            if (cand[j] > cur) f += __expf(2.0f * bf2f(unkey(cand[j])));
#pragma unroll
        for (int o = 1; o < 64; o <<= 1) {
            r += __shfl_xor(r, o);
            f += __shfl_xor(f, o);
        }
        const float S = f + (float)(64 - r) * __expf(2.0f * bf2f(unkey(cur)));

        // positives: bottom-8 via tournament over <=192 keys (3/lane)
        unsigned pk[3];
#pragma unroll
        for (int s = 0; s < 3; ++s) {
            int idx = lane * 3 + s;
            pk[s] = (idx < pc)
                ? ((((unsigned)pcand[(size_t)row * PCAP + idx]) << 9) |
                   ((unsigned)lane << 3) | (unsigned)s)
                : 0xFFFFFFFFu;
        }
        float acc = 0.f;
#pragma unroll
        for (int rd = 0; rd < 8; ++rd) {
            unsigned best = pk[0] < pk[1] ? pk[0] : pk[1];
            best = best < pk[2] ? best : pk[2];
#pragma unroll
            for (int o = 1; o < 64; o <<= 1) {
                unsigned v2 = (unsigned)__shfl_xor((int)best, o);
                best = best < v2 ? best : v2;
            }
            if (best != 0xFFFFFFFFu) {
                if (lane == (int)((best >> 3) & 63u)) pk[best & 7u] = 0xFFFFFFFFu;
                if (lane == 0) {
                    float p = bf2f(unkey(best >> 9));
                    acc += logf(__expf(2.0f * p) + S) - 2.0f * p;
                }
            }
        }
        if (lane == 0) out[row] = acc * 0.125f;
    } else {
        // ---- exact fallback (distribution-independent): bisect by recompute ----
        const int myc = tgb[row];
        const unsigned short* rowv = nf + (size_t)row * C_DIM;
        unsigned cur = 0;
        for (int bit = 15; bit >= 0; --bit) {
            unsigned trial = cur | (1u << bit);
            int cnt = 0;
            for (int c = lane; c < B_N; c += 64)
                if (tgb[c] != myc)
                    cnt += (dotkey(rowv, nf + (size_t)c * C_DIM) >= trial) ? 1 : 0;
#pragma unroll
            for (int o = 1; o < 64; o <<= 1) cnt += __shfl_xor(cnt, o);
            if (cnt >= 64) cur = trial;
        }
        int rstrict = 0; float f = 0.f;
        for (int c = lane; c < B_N; c += 64) {
            if (tgb[c] != myc) {
                unsigned k = dotkey(rowv, nf + (size_t)c * C_DIM);
                if (k > cur) { rstrict++; f += __expf(2.0f * bf2f(unkey(k))); }
            }
        }
#pragma unroll
        for (int o = 1; o < 64; o <<= 1) {
            rstrict += __shfl_xor(rstrict, o);
            f += __shfl_xor(f, o);
        }
        const float S = f + (float)(64 - rstrict) * __expf(2.0f * bf2f(unkey(cur)));
        unsigned last = 0;
        float acc = 0.f;
        for (int rd = 0; rd < 8; ++rd) {
            unsigned best = 0xFFFFFFFFu;
            for (int c = lane; c < B_N; c += 64) {
                if (tgb[c] == myc) {
                    unsigned k = dotkey(rowv, nf + (size_t)c * C_DIM);
                    unsigned p2 = (k << 13) | (unsigned)c;
                    if (p2 > last && p2 < best) best = p2;
                }
            }
#pragma unroll
            for (int o = 1; o < 64; o <<= 1) {
                unsigned v2 = (unsigned)__shfl_xor((int)best, o);
                best = best < v2 ? best : v2;
            }
            if (best == 0xFFFFFFFFu) break;
            last = best;
            if (lane == 0) {
                float p = bf2f(unkey(best >> 13));
                acc += logf(__expf(2.0f * p) + S) - 2.0f * p;
            }
        }
        if (lane == 0) out[row] = acc * 0.125f;
    }
}

extern "C" void kernel_launch(void* const* d_in, const int* in_sizes, int n_in,
                              void* d_out, int out_size, void* d_ws, size_t ws_size,
                              hipStream_t stream) {
    const float* newf = (const float*)d_in[1];
    const unsigned int* tgtw = (const unsigned int*)d_in[2];
    float* out = (float*)d_out;
    char* ws = (char*)d_ws;
    unsigned char* tgb = (unsigned char*)ws;                          // 8 KB
    unsigned* ncnt = (unsigned*)(ws + 8192);                          // 32 KB
    unsigned* pcnt = (unsigned*)(ws + 40960);                         // 32 KB
    unsigned short* ncand = (unsigned short*)(ws + 73728);            // 4 MB
    unsigned short* pcand = (unsigned short*)(ws + 73728 + (size_t)B_N * NCAP * 2);  // 3 MB
    unsigned short* nf = (unsigned short*)(ws + 8388608);             // 8 MB, aligned
    // total ~16.4 MB of d_ws used

    hipLaunchKernelGGL(zero_cnt, dim3(32), dim3(256), 0, stream, ncnt, pcnt);
    hipLaunchKernelGGL(prep_tgt, dim3(1), dim3(256), 0, stream, tgtw, tgb);
    hipLaunchKernelGGL(normalize_k, dim3(B_N / 4), dim3(256), 0, stream, newf, nf);
    hipLaunchKernelGGL(gemm_cand, dim3(NTRI), dim3(256), 0, stream,
                       nf, tgb, ncand, ncnt, pcand, pcnt);
    hipLaunchKernelGGL(select_loss, dim3(B_N / 4), dim3(256), 0, stream,
                       ncand, ncnt, pcand, pcnt, tgb, nf, out);
}

// Round 15
// 184.967 us; speedup vs baseline: 2.0302x; 2.0302x over previous
//
#include <hip/hip_runtime.h>
#include <hip/hip_bf16.h>

#define B_N 8192
#define C_DIM 512
#define NT 64            // 128-wide tiles per dimension
#define NTRI 2080        // NT*(NT+1)/2 upper-triangle tiles
#define TGKEY 0xBDC0u    // negkey(bf16 0.09375): conservative top-64 pre-threshold
#define CAP 16           // candidate slots per (row, tile)

typedef __attribute__((ext_vector_type(4))) float f32x4;
typedef __attribute__((ext_vector_type(8))) __bf16 bf16x8;
typedef __attribute__((address_space(3))) unsigned int lds_u32;
typedef const __attribute__((address_space(1))) unsigned int glb_u32;

__device__ __forceinline__ void gl_lds16(const unsigned short* g, unsigned short* l) {
    __builtin_amdgcn_global_load_lds((glb_u32*)g, (lds_u32*)l, 16, 0, 0);
}

__device__ __forceinline__ unsigned short f2bf(float f) {
    unsigned int u = __float_as_uint(f);
    u += 0x7FFFu + ((u >> 16) & 1u);          // RNE
    return (unsigned short)(u >> 16);
}
__device__ __forceinline__ float bf2f(unsigned int s) {
    return __uint_as_float(s << 16);
}
// order-preserving key: float order -> unsigned ascending. 0 / 0xFFFF impossible for finite sims.
__device__ __forceinline__ unsigned negkey(unsigned ub) {
    return (ub & 0x8000u) ? ((~ub) & 0xFFFFu) : (ub | 0x8000u);
}
__device__ __forceinline__ unsigned unkey(unsigned k) {
    return (k & 0x8000u) ? (k ^ 0x8000u) : ((~k) & 0xFFFFu);
}

// ---- detect int64-vs-int32 target layout, emit class bytes ----
__global__ void prep_tgt(const unsigned int* __restrict__ t, unsigned char* __restrict__ tgb) {
    __shared__ int bad;
    if (threadIdx.x == 0) bad = 0;
    __syncthreads();
    int local = 0;
    for (int k = (int)threadIdx.x; k < 4096; k += 256)   // first 32KB only: safe for both layouts
        if (t[2 * k + 1] != 0u) local = 1;
    if (local) atomicOr(&bad, 1);
    __syncthreads();
    const int is64 = (bad == 0);
    for (int j = (int)threadIdx.x; j < B_N; j += 256)
        tgb[j] = (unsigned char)(is64 ? t[2 * j] : t[j]);
}

// ---- L2 normalize rows, emit bf16 ----
__global__ __launch_bounds__(256) void normalize_k(const float* __restrict__ x,
                                                   unsigned short* __restrict__ nf) {
    const int wid = threadIdx.x >> 6, lane = threadIdx.x & 63;
    const size_t row = (size_t)blockIdx.x * 4 + wid;
    const float4* xr = (const float4*)(x + row * C_DIM) + lane * 2;
    float4 a = xr[0], b = xr[1];
    float ss = a.x * a.x + a.y * a.y + a.z * a.z + a.w * a.w +
               b.x * b.x + b.y * b.y + b.z * b.z + b.w * b.w;
#pragma unroll
    for (int m = 1; m < 64; m <<= 1) ss += __shfl_xor(ss, m);
    float sc = 1.0f / fmaxf(sqrtf(ss), 1e-12f);
    union { unsigned short s[8]; int4 v; } o;
    o.s[0] = f2bf(a.x * sc); o.s[1] = f2bf(a.y * sc);
    o.s[2] = f2bf(a.z * sc); o.s[3] = f2bf(a.w * sc);
    o.s[4] = f2bf(b.x * sc); o.s[5] = f2bf(b.y * sc);
    o.s[6] = f2bf(b.z * sc); o.s[7] = f2bf(b.w * sc);
    *(int4*)(nf + row * C_DIM + lane * 8) = o.v;
}

// ---- triangular GEMM; epilogue: LDS-aggregated candidates -> dense [tile][row][16] ----
__global__ __launch_bounds__(256) void gemm_cand(const unsigned short* __restrict__ nf,
                                                 const unsigned char* __restrict__ tgb,
                                                 unsigned short* __restrict__ ncand,
                                                 unsigned char* __restrict__ ncntg,
                                                 unsigned short* __restrict__ pcand,
                                                 unsigned char* __restrict__ pcntg) {
    __shared__ unsigned short smem[2 * 8192];           // As | Bs (32 KB); epilogue aliases
    unsigned short* As = smem;
    unsigned short* Bs = smem + 8192;
    const int idp = (NTRI - 1) - (int)blockIdx.x;       // row-major triangle order
    int u = (int)((sqrtf(8.0f * (float)idp + 1.0f) - 1.0f) * 0.5f);
    while (u * (u + 1) / 2 > idp) --u;
    while ((u + 1) * (u + 2) / 2 <= idp) ++u;
    const int v = idp - u * (u + 1) / 2;
    const int tI = (NT - 1) - u;
    const int tJ = (NT - 1) - v;

    const int tid = threadIdx.x;
    const int wid = tid >> 6, lane = tid & 63;
    const int wm = wid >> 1, wn = wid & 1;
    const int gr = tI * 128;
    const int gc = tJ * 128;
    f32x4 zero = {0.f, 0.f, 0.f, 0.f};
    f32x4 acc[4][4];
#pragma unroll
    for (int m = 0; m < 4; ++m)
#pragma unroll
        for (int n = 0; n < 4; ++n) acc[m][n] = zero;

    const int lr = lane >> 3, lcb = lane & 7;

    for (int k0 = 0; k0 < C_DIM; k0 += 64) {
#pragma unroll
        for (int i = 0; i < 4; ++i) {
            const int chunk = wid * 4 + i;
            const int r = chunk * 8 + lr;
            const int sc = (lcb ^ (r & 7)) << 3;        // inverse-swizzled source col
            gl_lds16(nf + (size_t)(gr + r) * C_DIM + k0 + sc, As + chunk * 512);
            gl_lds16(nf + (size_t)(gc + r) * C_DIM + k0 + sc, Bs + chunk * 512);
        }
        __syncthreads();
#pragma unroll
        for (int kk = 0; kk < 2; ++kk) {
            const int krow = kk * 32 + (lane >> 4) * 8;
            bf16x8 a[4], b[4];
#pragma unroll
            for (int m = 0; m < 4; ++m) {
                const int R = wm * 64 + m * 16 + (lane & 15);
                a[m] = *(const bf16x8*)&As[R * 64 + (krow ^ ((R & 7) << 3))];
            }
#pragma unroll
            for (int n = 0; n < 4; ++n) {
                const int R = wn * 64 + n * 16 + (lane & 15);
                b[n] = *(const bf16x8*)&Bs[R * 64 + (krow ^ ((R & 7) << 3))];
            }
#pragma unroll
            for (int m = 0; m < 4; ++m)
#pragma unroll
                for (int n = 0; n < 4; ++n)
                    acc[m][n] = __builtin_amdgcn_mfma_f32_16x16x32_bf16(a[m], b[n], acc[m][n], 0, 0, 0);
        }
        __syncthreads();                                 // smem dead after final iter
    }

    // ---- epilogue: LDS candidate lists for 256 logical rows (0-127 tile rows, 128-255 cols)
    unsigned short* negL = smem;                         // 256*16 shorts
    unsigned short* posL = smem + 4096;                  // 256*16 shorts
    int* cntN = (int*)(smem + 8192);                     // 256 ints
    int* cntP = (int*)(smem + 8704);                     // 256 ints
    cntN[tid] = 0; cntP[tid] = 0;
    __syncthreads();

    const int fr = (lane >> 4) << 2;
    const int fc = lane & 15;
    const bool mirror = (tJ > tI);
    unsigned char cc[4], rc[4][4];
#pragma unroll
    for (int n = 0; n < 4; ++n) cc[n] = tgb[gc + wn * 64 + n * 16 + fc];
#pragma unroll
    for (int m = 0; m < 4; ++m)
#pragma unroll
        for (int j = 0; j < 4; ++j) rc[m][j] = tgb[gr + wm * 64 + m * 16 + fr + j];

#pragma unroll
    for (int m = 0; m < 4; ++m)
#pragma unroll
        for (int n = 0; n < 4; ++n) {
            const int c_loc = 128 + wn * 64 + n * 16 + fc;
#pragma unroll
            for (int j = 0; j < 4; ++j) {
                const int r_loc = wm * 64 + m * 16 + fr + j;
                const unsigned key = negkey(f2bf(acc[m][n][j]));
                if (rc[m][j] == cc[n]) {
                    int p = atomicAdd(&cntP[r_loc], 1);
                    if (p < CAP) posL[r_loc * CAP + p] = (unsigned short)key;
                    if (mirror) {
                        int p2 = atomicAdd(&cntP[c_loc], 1);
                        if (p2 < CAP) posL[c_loc * CAP + p2] = (unsigned short)key;
                    }
                } else if (key > TGKEY) {
                    int p = atomicAdd(&cntN[r_loc], 1);
                    if (p < CAP) negL[r_loc * CAP + p] = (unsigned short)key;
                    if (mirror) {
                        int p2 = atomicAdd(&cntN[c_loc], 1);
                        if (p2 < CAP) negL[c_loc * CAP + p2] = (unsigned short)key;
                    }
                }
            }
        }
    __syncthreads();

    // ---- pack: thread t -> logical row t (cols half only when mirror) ----
    const int half = tid >> 7, lr2 = tid & 127;
    if (half == 0 || mirror) {
        const int grow = half ? (gc + lr2) : (gr + lr2);
        const int gtile = half ? tI : tJ;
        const size_t slot = (size_t)gtile * B_N + grow;
        int cn = cntN[tid], cp = cntP[tid];
        ncntg[slot] = (unsigned char)(cn > 255 ? 255 : cn);
        pcntg[slot] = (unsigned char)(cp > 255 ? 255 : cp);
        *(int4*)&ncand[slot * CAP] = *(int4*)&negL[tid * CAP];
        *(int4*)&ncand[slot * CAP + 8] = *(int4*)&negL[tid * CAP + 8];
        *(int4*)&pcand[slot * CAP] = *(int4*)&posL[tid * CAP];
        *(int4*)&pcand[slot * CAP + 8] = *(int4*)&posL[tid * CAP + 8];
    }
}

// fallback helper: recompute one sim key from nf (exact, self-consistent per row)
__device__ unsigned dotkey(const unsigned short* __restrict__ a,
                           const unsigned short* __restrict__ b) {
    float s = 0.f;
    for (int d = 0; d < C_DIM; d += 8) {
        float p = 0.f;
#pragma unroll
        for (int e = 0; e < 8; ++e)
            p += bf2f(a[d + e]) * bf2f(b[d + e]);
        s += p;
    }
    return negkey(f2bf(s));
}

// ---- wave-per-row selection + loss: lane j owns tile j; no LDS, no barriers ----
__global__ __launch_bounds__(256) void select_loss(
        const unsigned short* __restrict__ ncand, const unsigned char* __restrict__ ncntg,
        const unsigned short* __restrict__ pcand, const unsigned char* __restrict__ pcntg,
        const unsigned char* __restrict__ tgb, const unsigned short* __restrict__ nf,
        float* __restrict__ out) {
    const int wid = threadIdx.x >> 6, lane = threadIdx.x & 63;
    const int row = blockIdx.x * 4 + wid;
    const size_t slot = (size_t)lane * B_N + row;

    const int cn = ncntg[slot], cp = pcntg[slot];
    const bool ovf = (cn > CAP) || (cp > CAP);
    const unsigned long long ovfm = __ballot(ovf);
    int nctot = cn > CAP ? CAP : cn;
#pragma unroll
    for (int o = 1; o < 64; o <<= 1) nctot += __shfl_xor(nctot, o);

    if (ovfm == 0 && nctot >= 64) {
        // ---- fast path ----
        union { int4 v[2]; unsigned short s[16]; } N, P;
        N.v[0] = *(const int4*)&ncand[slot * CAP];
        N.v[1] = *(const int4*)&ncand[slot * CAP + 8];
        P.v[0] = *(const int4*)&pcand[slot * CAP];
        P.v[1] = *(const int4*)&pcand[slot * CAP + 8];
#pragma unroll
        for (int s = 0; s < 16; ++s) {
            if (s >= cn) N.s[s] = 0;
            if (s >= cp) P.s[s] = 0xFFFFu;               // sentinel (impossible real key)
        }
        // 16-step bisection: exact 64th-largest key among all keys > TGKEY
        unsigned cur = 0;
#pragma unroll
        for (int bit = 15; bit >= 0; --bit) {
            unsigned trial = cur | (1u << bit);
            int c = 0;
#pragma unroll
            for (int s = 0; s < 16; ++s) c += (N.s[s] >= trial) ? 1 : 0;
#pragma unroll
            for (int o = 1; o < 64; o <<= 1) c += __shfl_xor(c, o);
            if (c >= 64) cur = trial;
        }
        int r = 0; float f = 0.f;
#pragma unroll
        for (int s = 0; s < 16; ++s)
            if (N.s[s] > cur) { r++; f += __expf(2.0f * bf2f(unkey(N.s[s]))); }
#pragma unroll
        for (int o = 1; o < 64; o <<= 1) {
            r += __shfl_xor(r, o);
            f += __shfl_xor(f, o);
        }
        const float S = f + (float)(64 - r) * __expf(2.0f * bf2f(unkey(cur)));

        // positives: bottom-8 tournament over lane-local slots
        float acc = 0.f;
#pragma unroll
        for (int rd = 0; rd < 8; ++rd) {
            unsigned best = 0xFFFFFFFFu;
#pragma unroll
            for (int s = 0; s < 16; ++s) {
                unsigned cnd = (((unsigned)P.s[s]) << 10) | ((unsigned)lane << 4) | (unsigned)s;
                best = best < cnd ? best : cnd;
            }
#pragma unroll
            for (int o = 1; o < 64; o <<= 1) {
                unsigned v2 = (unsigned)__shfl_xor((int)best, o);
                best = best < v2 ? best : v2;
            }
            if ((best >> 10) == 0xFFFFu) break;          // no positives left
            if (lane == (int)((best >> 4) & 63u)) P.s[best & 15u] = 0xFFFFu;
            if (lane == 0) {
                float p = bf2f(unkey(best >> 10));
                acc += logf(__expf(2.0f * p) + S) - 2.0f * p;
            }
        }
        if (lane == 0) out[row] = acc * 0.125f;
    } else {
        // ---- exact fallback (distribution-independent): bisect by recompute ----
        const int myc = tgb[row];
        const unsigned short* rowv = nf + (size_t)row * C_DIM;
        unsigned cur = 0;
        for (int bit = 15; bit >= 0; --bit) {
            unsigned trial = cur | (1u << bit);
            int cnt = 0;
            for (int c = lane; c < B_N; c += 64)
                if (tgb[c] != myc)
                    cnt += (dotkey(rowv, nf + (size_t)c * C_DIM) >= trial) ? 1 : 0;
#pragma unroll
            for (int o = 1; o < 64; o <<= 1) cnt += __shfl_xor(cnt, o);
            if (cnt >= 64) cur = trial;
        }
        int rstrict = 0; float f = 0.f;
        for (int c = lane; c < B_N; c += 64) {
            if (tgb[c] != myc) {
                unsigned k = dotkey(rowv, nf + (size_t)c * C_DIM);
                if (k > cur) { rstrict++; f += __expf(2.0f * bf2f(unkey(k))); }
            }
        }
#pragma unroll
        for (int o = 1; o < 64; o <<= 1) {
            rstrict += __shfl_xor(rstrict, o);
            f += __shfl_xor(f, o);
        }
        const float S = f + (float)(64 - rstrict) * __expf(2.0f * bf2f(unkey(cur)));
        unsigned last = 0;
        float acc = 0.f;
        for (int rd = 0; rd < 8; ++rd) {
            unsigned best = 0xFFFFFFFFu;
            for (int c = lane; c < B_N; c += 64) {
                if (tgb[c] == myc) {
                    unsigned k = dotkey(rowv, nf + (size_t)c * C_DIM);
                    unsigned p2 = (k << 13) | (unsigned)c;
                    if (p2 > last && p2 < best) best = p2;
                }
            }
#pragma unroll
            for (int o = 1; o < 64; o <<= 1) {
                unsigned v2 = (unsigned)__shfl_xor((int)best, o);
                best = best < v2 ? best : v2;
            }
            if (best == 0xFFFFFFFFu) break;
            last = best;
            if (lane == 0) {
                float p = bf2f(unkey(best >> 13));
                acc += logf(__expf(2.0f * p) + S) - 2.0f * p;
            }
        }
        if (lane == 0) out[row] = acc * 0.125f;
    }
}

extern "C" void kernel_launch(void* const* d_in, const int* in_sizes, int n_in,
                              void* d_out, int out_size, void* d_ws, size_t ws_size,
                              hipStream_t stream) {
    const float* newf = (const float*)d_in[1];
    const unsigned int* tgtw = (const unsigned int*)d_in[2];
    float* out = (float*)d_out;
    char* ws = (char*)d_ws;
    unsigned char* tgb  = (unsigned char*)ws;                         // 8 KB
    unsigned char* ncntg = (unsigned char*)(ws + (1u << 20));         // 512 KB @ 1 MB
    unsigned char* pcntg = (unsigned char*)(ws + (1u << 20) + (1u << 19));
    unsigned short* nf   = (unsigned short*)(ws + (2u << 20));        // 8 MB @ 2 MB
    unsigned short* ncand = (unsigned short*)(ws + (10u << 20));      // 16 MB @ 10 MB
    unsigned short* pcand = (unsigned short*)(ws + (26u << 20));      // 16 MB @ 26 MB
    // total 42 MB of d_ws (prior rounds used ~140 MB)

    hipLaunchKernelGGL(prep_tgt, dim3(1), dim3(256), 0, stream, tgtw, tgb);
    hipLaunchKernelGGL(normalize_k, dim3(B_N / 4), dim3(256), 0, stream, newf, nf);
    hipLaunchKernelGGL(gemm_cand, dim3(NTRI), dim3(256), 0, stream,
                       nf, tgb, ncand, ncntg, pcand, pcntg);
    hipLaunchKernelGGL(select_loss, dim3(B_N / 4), dim3(256), 0, stream,
                       ncand, ncntg, pcand, pcntg, tgb, nf, out);
}

// Round 16
// 136.134 us; speedup vs baseline: 2.7585x; 1.3587x over previous
//
#include <hip/hip_runtime.h>
#include <hip/hip_bf16.h>

#define B_N 8192
#define C_DIM 512
#define NT 64            // 128-wide tiles per dimension
#define NTRI 2080        // NT*(NT+1)/2 upper-triangle tiles
#define TGKEY 0xBDC0u    // negkey(bf16 0.09375): conservative top-64 pre-threshold

typedef __attribute__((ext_vector_type(4))) float f32x4;
typedef __attribute__((address_space(3))) unsigned int lds_u32;
typedef const __attribute__((address_space(1))) unsigned int glb_u32;

__device__ __forceinline__ void gl_lds16b(const unsigned char* g, unsigned char* l) {
    __builtin_amdgcn_global_load_lds((glb_u32*)g, (lds_u32*)l, 16, 0, 0);
}

__device__ __forceinline__ unsigned short f2bf(float f) {
    unsigned int u = __float_as_uint(f);
    u += 0x7FFFu + ((u >> 16) & 1u);          // RNE
    return (unsigned short)(u >> 16);
}
__device__ __forceinline__ float bf2f(unsigned int s) {
    return __uint_as_float(s << 16);
}
// order-preserving key: float order -> unsigned ascending. key 0 impossible for finite sims.
__device__ __forceinline__ unsigned negkey(unsigned ub) {
    return (ub & 0x8000u) ? ((~ub) & 0xFFFFu) : (ub | 0x8000u);
}
__device__ __forceinline__ unsigned unkey(unsigned k) {
    return (k & 0x8000u) ? (k ^ 0x8000u) : ((~k) & 0xFFFFu);
}

// ---- one-block prep: layout detect, class bytes, class member lists (counting sort) ----
__global__ void prep_all(const unsigned int* __restrict__ t, unsigned char* __restrict__ tgb,
                         unsigned short* __restrict__ clist, int* __restrict__ off) {
    __shared__ int bad, cnt[128], base[128];
    const int tid = threadIdx.x;
    if (tid == 0) bad = 0;
    if (tid < 128) cnt[tid] = 0;
    __syncthreads();
    int local = 0;
    for (int k = tid; k < 4096; k += 256)        // first 32KB only: safe for both layouts
        if (t[2 * k + 1] != 0u) local = 1;
    if (local) atomicOr(&bad, 1);
    __syncthreads();
    const int is64 = (bad == 0);
    for (int i = 0; i < 32; ++i) {
        int j = i * 256 + tid;
        unsigned c = (is64 ? t[2 * j] : t[j]) & 127u;   // classes < 100
        tgb[j] = (unsigned char)c;
        atomicAdd(&cnt[c], 1);
    }
    __syncthreads();
    if (tid == 0) {
        int s = 0;
        for (int c = 0; c < 128; ++c) { base[c] = s; off[c] = s; s += cnt[c]; }
        off[128] = s;
    }
    __syncthreads();
    for (int i = 0; i < 32; ++i) {
        int j = i * 256 + tid;
        unsigned c = (is64 ? t[2 * j] : t[j]) & 127u;
        int idx = atomicAdd(&base[c], 1);
        clist[idx] = (unsigned short)j;
    }
}

// ---- per-class membership words: cm2[c*256+t] bit (q*8+e) = (tgb[q*2048+t*8+e]==c) ----
__global__ void class_masks(const unsigned char* __restrict__ tgb,
                            unsigned int* __restrict__ cm2) {
    const int c = blockIdx.x, t = threadIdx.x;
    unsigned w = 0;
#pragma unroll
    for (int q = 0; q < 4; ++q) {
        const unsigned char* base = tgb + q * 2048 + t * 8;
        unsigned b = 0;
#pragma unroll
        for (int e = 0; e < 8; ++e)
            b |= ((unsigned)(base[e] == c)) << e;
        w |= b << (8 * q);
    }
    cm2[c * 256 + t] = w;
}

// ---- L2 normalize rows, emit OCP e4m3 fp8 ----
__global__ __launch_bounds__(256) void normalize_k(const float* __restrict__ x,
                                                   unsigned char* __restrict__ nf8) {
    const int wid = threadIdx.x >> 6, lane = threadIdx.x & 63;
    const size_t row = (size_t)blockIdx.x * 4 + wid;
    const float4* xr = (const float4*)(x + row * C_DIM) + lane * 2;
    float4 a = xr[0], b = xr[1];
    float ss = a.x * a.x + a.y * a.y + a.z * a.z + a.w * a.w +
               b.x * b.x + b.y * b.y + b.z * b.z + b.w * b.w;
#pragma unroll
    for (int m = 1; m < 64; m <<= 1) ss += __shfl_xor(ss, m);
    float sc = 1.0f / fmaxf(sqrtf(ss), 1e-12f);
    int w0 = __builtin_amdgcn_cvt_pk_fp8_f32(a.x * sc, a.y * sc, 0, false);
    w0 = __builtin_amdgcn_cvt_pk_fp8_f32(a.z * sc, a.w * sc, w0, true);
    int w1 = __builtin_amdgcn_cvt_pk_fp8_f32(b.x * sc, b.y * sc, 0, false);
    w1 = __builtin_amdgcn_cvt_pk_fp8_f32(b.z * sc, b.w * sc, w1, true);
    int2 o2; o2.x = w0; o2.y = w1;
    *(int2*)(nf8 + row * C_DIM + lane * 8) = o2;
}

// ---- sim keys = negkey(bf16(nf8 @ nf8^T)), fp8 MFMA, 128x128 tiles, R13 structure ----
// staging: 16-B-granular XOR swizzle (colblock ^= row&3), fragment b64 reads 2-way/bank.
__global__ __launch_bounds__(256) void gemm_sim(const unsigned char* __restrict__ nf8,
                                                unsigned short* __restrict__ simk,
                                                int rowBase, int symmetric) {
    __shared__ __align__(16) unsigned char smemB[34816];   // As8|Bs8 (16KB); Cs aliases
    unsigned char* As8 = smemB;
    unsigned char* Bs8 = smemB + 8192;
    int tI, tJ;
    if (symmetric) {
        const int idp = (NTRI - 1) - (int)blockIdx.x;   // row-major triangle order
        int u = (int)((sqrtf(8.0f * (float)idp + 1.0f) - 1.0f) * 0.5f);
        while (u * (u + 1) / 2 > idp) --u;
        while ((u + 1) * (u + 2) / 2 <= idp) ++u;
        const int v = idp - u * (u + 1) / 2;
        tI = (NT - 1) - u;
        tJ = (NT - 1) - v;
    } else {
        tI = blockIdx.y; tJ = blockIdx.x;
    }
    const int tid = threadIdx.x;
    const int wid = tid >> 6, lane = tid & 63;
    const int wm = wid >> 1, wn = wid & 1;
    const int gr = rowBase + tI * 128;
    const int gc = tJ * 128;
    f32x4 zero = {0.f, 0.f, 0.f, 0.f};
    f32x4 acc[4][4];
#pragma unroll
    for (int m = 0; m < 4; ++m)
#pragma unroll
        for (int n = 0; n < 4; ++n) acc[m][n] = zero;

    const int lr = lane >> 2, lcb = lane & 3;           // chunk = 16 rows x 64 B

    for (int k0 = 0; k0 < C_DIM; k0 += 64) {
#pragma unroll
        for (int i = 0; i < 2; ++i) {
            const int chunk = wid * 2 + i;              // 0..7, wave-uniform
            const int r = chunk * 16 + lr;
            const int sc = (lcb ^ (r & 3)) << 4;        // inverse-swizzled source col-block
            gl_lds16b(nf8 + (size_t)(gr + r) * C_DIM + k0 + sc, As8 + chunk * 1024);
            gl_lds16b(nf8 + (size_t)(gc + r) * C_DIM + k0 + sc, Bs8 + chunk * 1024);
        }
        __syncthreads();
#pragma unroll
        for (int kk = 0; kk < 2; ++kk) {
            const int krow = kk * 32 + (lane >> 4) * 8; // byte offset of 8-elem k-chunk
            long a[4], b[4];
#pragma unroll
            for (int m = 0; m < 4; ++m) {
                const int R = wm * 64 + m * 16 + (lane & 15);
                a[m] = *(const long*)&As8[R * 64 + (krow ^ ((R & 3) << 4))];
            }
#pragma unroll
            for (int n = 0; n < 4; ++n) {
                const int R = wn * 64 + n * 16 + (lane & 15);
                b[n] = *(const long*)&Bs8[R * 64 + (krow ^ ((R & 3) << 4))];
            }
#pragma unroll
            for (int m = 0; m < 4; ++m)
#pragma unroll
                for (int n = 0; n < 4; ++n)
                    acc[m][n] = __builtin_amdgcn_mfma_f32_16x16x32_fp8_fp8(a[m], b[n], acc[m][n], 0, 0, 0);
        }
        __syncthreads();
    }

    // pre-pack keys once; C/D layout: col=lane&15, row=(lane>>4)*4+j
    unsigned short kk4[4][4][4];
#pragma unroll
    for (int m = 0; m < 4; ++m)
#pragma unroll
        for (int n = 0; n < 4; ++n)
#pragma unroll
            for (int j = 0; j < 4; ++j)
                kk4[m][n][j] = (unsigned short)negkey(f2bf(acc[m][n][j]));

    unsigned short* Cs = (unsigned short*)smemB;         // 128*136 shorts = 34816 B
    const int fc = (lane & 15);
    const int fr = (lane >> 4) << 2;

    // ---- direct (row-major) write via row-major bounce ----
#pragma unroll
    for (int m = 0; m < 4; ++m)
#pragma unroll
        for (int n = 0; n < 4; ++n) {
            const int c = wn * 64 + n * 16 + fc;
            const int r0 = wm * 64 + m * 16 + fr;
#pragma unroll
            for (int j = 0; j < 4; ++j)
                Cs[(r0 + j) * 136 + c] = kk4[m][n][j];
        }
    __syncthreads();
#pragma unroll
    for (int k = 0; k < 8; ++k) {
        const int lin = tid + k * 256;
        const int r = lin >> 4;
        const int c0 = (lin & 15) * 8;
        int4 v = *(const int4*)&Cs[r * 136 + c0];
        *(int4*)&simk[(size_t)(gr - rowBase + r) * B_N + gc + c0] = v;
    }

    if (symmetric && tJ > tI) {
        // ---- transposed write via col-major bounce ----
        __syncthreads();
#pragma unroll
        for (int m = 0; m < 4; ++m)
#pragma unroll
            for (int n = 0; n < 4; ++n) {
                const int c = wn * 64 + n * 16 + fc;
                const int r0 = wm * 64 + m * 16 + fr;
                ushort4 pk;
                pk.x = kk4[m][n][0]; pk.y = kk4[m][n][1];
                pk.z = kk4[m][n][2]; pk.w = kk4[m][n][3];
                *(ushort4*)&Cs[c * 136 + r0] = pk;
            }
        __syncthreads();
#pragma unroll
        for (int k = 0; k < 8; ++k) {
            const int lin = tid + k * 256;
            const int c = lin >> 4;
            const int r0 = (lin & 15) * 8;
            int4 v = *(const int4*)&Cs[c * 136 + r0];
            *(int4*)&simk[(size_t)(gc + c) * B_N + gr + r0] = v;
        }
    }
}

// ---- block-per-row selection + loss: candidate compaction above TGKEY, exact bisect ----
__global__ __launch_bounds__(256) void select_loss(const unsigned short* __restrict__ simk,
                                                   const unsigned char* __restrict__ tgb,
                                                   const unsigned int* __restrict__ cm2,
                                                   const unsigned short* __restrict__ clist,
                                                   const int* __restrict__ off,
                                                   float* __restrict__ out, int rowBase) {
    __shared__ int nlist[256];
    __shared__ float s_partial[4];
    __shared__ int nln, s_cnt;

    const int tid = threadIdx.x;
    const int wid = tid >> 6, lane = tid & 63;
    const int row = rowBase + blockIdx.x;
    const unsigned short* srow = simk + (size_t)blockIdx.x * B_N;
    const int ti = tgb[row];
    const int o0 = off[ti], o1 = off[ti + 1];

    // load 32 keys, mask same-class halves to 0 (key 0 < TGKEY: never a candidate)
    int4 A[4];
    const unsigned m = cm2[ti * 256 + tid];
#pragma unroll
    for (int q = 0; q < 4; ++q) {
        A[q] = *(const int4*)(srow + q * 2048 + tid * 8);
#pragma unroll
        for (int d = 0; d < 4; ++d) {
            unsigned two = (m >> (q * 8 + d * 2)) & 3u;
            unsigned kill = ((two & 1u) * 0xFFFFu) | (((two >> 1) & 1u) * 0xFFFF0000u);
            int v = (d == 0 ? A[q].x : d == 1 ? A[q].y : d == 2 ? A[q].z : A[q].w);
            v = (int)((unsigned)v & ~kill);
            if (d == 0) A[q].x = v; else if (d == 1) A[q].y = v;
            else if (d == 2) A[q].z = v; else A[q].w = v;
        }
    }
    if (tid == 0) { nln = 0; s_cnt = 0; }
    __syncthreads();                                             // B1

#define ELEM_LOOP(BODY)                                                          \
    _Pragma("unroll")                                                            \
    for (int q = 0; q < 4; ++q) {                                                \
        _Pragma("unroll")                                                        \
        for (int d = 0; d < 4; ++d) {                                            \
            unsigned w32 = (unsigned)(d == 0 ? A[q].x : d == 1 ? A[q].y          \
                                    : d == 2 ? A[q].z : A[q].w);                 \
            _Pragma("unroll")                                                    \
            for (int h2 = 0; h2 < 2; ++h2) {                                     \
                unsigned key = h2 ? (w32 >> 16) : (w32 & 0xFFFFu);               \
                BODY                                                             \
            }                                                                    \
        }                                                                        \
    }

    // single scan: compact candidates above the conservative pre-threshold
    ELEM_LOOP(
        if (key > TGKEY) { int p = atomicAdd(&nln, 1); if (p < 256) nlist[p] = (int)key; }
    )
    __syncthreads();                                             // B2
    const int NC = nln;

    unsigned thr;
    int kremf;
    float S;

    if (NC >= 64 && NC <= 256) {
        // -------- fast path: wave0 solo; waves 1-3 exit now --------
        if (wid != 0) return;
        unsigned pk[8];
#pragma unroll
        for (int s2 = 0; s2 < 8; ++s2) {
            int idx = o0 + lane + s2 * 64;
            pk[s2] = (idx < o1)
                ? ((((unsigned)srow[clist[idx]]) << 9) | ((unsigned)lane << 3) | (unsigned)s2)
                : 0xFFFFFFFFu;
        }
        int4 cw = *(const int4*)&nlist[lane * 4];
        unsigned cand[4] = {(unsigned)cw.x, (unsigned)cw.y, (unsigned)cw.z, (unsigned)cw.w};
#pragma unroll
        for (int j = 0; j < 4; ++j)
            if (lane * 4 + j >= NC) cand[j] = 0;
        unsigned cur = 0;
#pragma unroll
        for (int bit = 15; bit >= 0; --bit) {
            unsigned trial = cur | (1u << bit);
            int c = (cand[0] >= trial) + (cand[1] >= trial) +
                    (cand[2] >= trial) + (cand[3] >= trial);
#pragma unroll
            for (int o = 1; o < 64; o <<= 1) c += __shfl_xor(c, o);
            if (c >= 64) cur = trial;
        }
        int r = (cand[0] > cur) + (cand[1] > cur) + (cand[2] > cur) + (cand[3] > cur);
#pragma unroll
        for (int o = 1; o < 64; o <<= 1) r += __shfl_xor(r, o);
        kremf = 64 - r;
        float f = 0.f;
#pragma unroll
        for (int j = 0; j < 4; ++j)
            if (cand[j] > cur) f += __expf(2.0f * bf2f(unkey(cand[j])));
#pragma unroll
        for (int o = 1; o < 64; o <<= 1) f += __shfl_xor(f, o);
        S = f;
        thr = cur;

        S += (float)kremf * __expf(2.0f * bf2f(unkey(thr)));
        float acc = 0.f;
#pragma unroll
        for (int rd = 0; rd < 8; ++rd) {
            unsigned best = pk[0];
#pragma unroll
            for (int s2 = 1; s2 < 8; ++s2) best = best < pk[s2] ? best : pk[s2];
#pragma unroll
            for (int o = 1; o < 64; o <<= 1) {
                unsigned v = (unsigned)__shfl_xor((int)best, o);
                best = best < v ? best : v;
            }
            if (best != 0xFFFFFFFFu) {
                if (lane == (int)((best >> 3) & 63u)) pk[best & 7u] = 0xFFFFFFFFu;
                if (lane == 0) {
                    float p = bf2f(unkey(best >> 9));
                    acc += logf(__expf(2.0f * p) + S) - 2.0f * p;
                }
            }
        }
        if (lane == 0) out[row] = acc * 0.125f;
    } else {
        // -------- exact fallback (distribution-independent): block-wide bisection --------
        unsigned cur = 0;
        for (int bit = 15; bit >= 0; --bit) {
            unsigned trial = cur | (1u << bit);
            int c = 0;
            ELEM_LOOP( c += (key >= trial) ? 1 : 0; )
#pragma unroll
            for (int o = 1; o < 64; o <<= 1) c += __shfl_xor(c, o);
            if (lane == 0) atomicAdd(&s_cnt, c);
            __syncthreads();
            int tot = s_cnt;
            __syncthreads();
            if (tid == 0) s_cnt = 0;
            __syncthreads();
            if (tot >= 64) cur = trial;
        }
        {
            int c = 0;
            ELEM_LOOP( c += (key > cur) ? 1 : 0; )
#pragma unroll
            for (int o = 1; o < 64; o <<= 1) c += __shfl_xor(c, o);
            if (lane == 0) atomicAdd(&s_cnt, c);
            __syncthreads();
        }
        const int r = s_cnt;
        kremf = 64 - r;
        {
            float f = 0.f;
            ELEM_LOOP( if (key > cur) f += __expf(2.0f * bf2f(unkey(key))); )
#pragma unroll
            for (int o = 1; o < 64; o <<= 1) f += __shfl_xor(f, o);
            if (lane == 0) s_partial[wid] = f;
            __syncthreads();
        }
        if (wid != 0) return;
        S = s_partial[0] + s_partial[1] + s_partial[2] + s_partial[3];
        thr = cur;

        unsigned pk[8];
#pragma unroll
        for (int s2 = 0; s2 < 8; ++s2) {
            int idx = o0 + lane + s2 * 64;
            pk[s2] = (idx < o1)
                ? ((((unsigned)srow[clist[idx]]) << 9) | ((unsigned)lane << 3) | (unsigned)s2)
                : 0xFFFFFFFFu;
        }
        S += (float)kremf * __expf(2.0f * bf2f(unkey(thr)));
        float acc = 0.f;
#pragma unroll
        for (int rd = 0; rd < 8; ++rd) {
            unsigned best = pk[0];
#pragma unroll
            for (int s2 = 1; s2 < 8; ++s2) best = best < pk[s2] ? best : pk[s2];
#pragma unroll
            for (int o = 1; o < 64; o <<= 1) {
                unsigned v = (unsigned)__shfl_xor((int)best, o);
                best = best < v ? best : v;
            }
            if (best != 0xFFFFFFFFu) {
                if (lane == (int)((best >> 3) & 63u)) pk[best & 7u] = 0xFFFFFFFFu;
                if (lane == 0) {
                    float p = bf2f(unkey(best >> 9));
                    acc += logf(__expf(2.0f * p) + S) - 2.0f * p;
                }
            }
        }
        if (lane == 0) out[row] = acc * 0.125f;
    }
#undef ELEM_LOOP
}

extern "C" void kernel_launch(void* const* d_in, const int* in_sizes, int n_in,
                              void* d_out, int out_size, void* d_ws, size_t ws_size,
                              hipStream_t stream) {
    const float* newf = (const float*)d_in[1];
    const unsigned int* tgtw = (const unsigned int*)d_in[2];
    float* out = (float*)d_out;
    char* ws = (char*)d_ws;
    unsigned char* tgb = (unsigned char*)ws;                          // 8 KB
    unsigned int* cm2 = (unsigned int*)(ws + 8192);                   // 100 KB
    int* off = (int*)(ws + 110592);                                   // 1 KB (129 ints)
    unsigned short* clist = (unsigned short*)(ws + 111616);           // 16 KB
    unsigned char* nf8 = (unsigned char*)(ws + 131072);               // 4 MB fp8 (aligned)
    unsigned short* simk = (unsigned short*)(ws + 131072 + ((size_t)4 << 20));

    size_t fixed = 131072 + ((size_t)4 << 20);
    size_t avail = (ws_size > fixed) ? (ws_size - fixed) : 0;
    long maxRows = (long)(avail / ((size_t)B_N * 2));
    int chunk = (int)((maxRows / 128) * 128);
    if (chunk < 128) chunk = 128;
    if (chunk > B_N) chunk = B_N;

    hipLaunchKernelGGL(prep_all, dim3(1), dim3(256), 0, stream, tgtw, tgb, clist, off);
    hipLaunchKernelGGL(class_masks, dim3(100), dim3(256), 0, stream, tgb, cm2);
    hipLaunchKernelGGL(normalize_k, dim3(B_N / 4), dim3(256), 0, stream, newf, nf8);
    if (chunk == B_N) {
        hipLaunchKernelGGL(gemm_sim, dim3(NTRI), dim3(256), 0, stream, nf8, simk, 0, 1);
        hipLaunchKernelGGL(select_loss, dim3(B_N), dim3(256), 0, stream,
                           simk, tgb, cm2, clist, off, out, 0);
    } else {
        for (int r0 = 0; r0 < B_N; r0 += chunk) {
            int rows = (B_N - r0 < chunk) ? (B_N - r0) : chunk;
            hipLaunchKernelGGL(gemm_sim, dim3(64, rows / 128), dim3(256), 0, stream,
                               nf8, simk, r0, 0);
            hipLaunchKernelGGL(select_loss, dim3(rows), dim3(256), 0, stream,
                               simk, tgb, cm2, clist, off, out, r0);
        }
    }
}

// Round 17
// 123.259 us; speedup vs baseline: 3.0467x; 1.1045x over previous
//
#include <hip/hip_runtime.h>
#include <hip/hip_bf16.h>

#define B_N 8192
#define C_DIM 512
#define NT 64            // 128-wide tiles per dimension
#define NTRI 2080        // NT*(NT+1)/2 upper-triangle tiles
#define TGKEY 0xBDC0u    // negkey(bf16 0.09375): conservative top-64 pre-threshold

typedef __attribute__((ext_vector_type(4))) float f32x4;
typedef __attribute__((address_space(3))) unsigned int lds_u32;
typedef const __attribute__((address_space(1))) unsigned int glb_u32;

__device__ __forceinline__ void gl_lds16b(const unsigned char* g, unsigned char* l) {
    __builtin_amdgcn_global_load_lds((glb_u32*)g, (lds_u32*)l, 16, 0, 0);
}

__device__ __forceinline__ unsigned short f2bf(float f) {
    unsigned int u = __float_as_uint(f);
    u += 0x7FFFu + ((u >> 16) & 1u);          // RNE
    return (unsigned short)(u >> 16);
}
__device__ __forceinline__ float bf2f(unsigned int s) {
    return __uint_as_float(s << 16);
}
// order-preserving key: float order -> unsigned ascending. key 0 impossible for finite sims.
__device__ __forceinline__ unsigned negkey(unsigned ub) {
    return (ub & 0x8000u) ? ((~ub) & 0xFFFFu) : (ub | 0x8000u);
}
__device__ __forceinline__ unsigned unkey(unsigned k) {
    return (k & 0x8000u) ? (k ^ 0x8000u) : ((~k) & 0xFFFFu);
}

// ---- one-block prep: layout detect, class bytes, class member lists (counting sort) ----
__global__ void prep_all(const unsigned int* __restrict__ t, unsigned char* __restrict__ tgb,
                         unsigned short* __restrict__ clist, int* __restrict__ off) {
    __shared__ int bad, cnt[128], base[128];
    const int tid = threadIdx.x;
    if (tid == 0) bad = 0;
    if (tid < 128) cnt[tid] = 0;
    __syncthreads();
    int local = 0;
    for (int k = tid; k < 4096; k += 256)        // first 32KB only: safe for both layouts
        if (t[2 * k + 1] != 0u) local = 1;
    if (local) atomicOr(&bad, 1);
    __syncthreads();
    const int is64 = (bad == 0);
    for (int i = 0; i < 32; ++i) {
        int j = i * 256 + tid;
        unsigned c = (is64 ? t[2 * j] : t[j]) & 127u;   // classes < 100
        tgb[j] = (unsigned char)c;
        atomicAdd(&cnt[c], 1);
    }
    __syncthreads();
    if (tid == 0) {
        int s = 0;
        for (int c = 0; c < 128; ++c) { base[c] = s; off[c] = s; s += cnt[c]; }
        off[128] = s;
    }
    __syncthreads();
    for (int i = 0; i < 32; ++i) {
        int j = i * 256 + tid;
        unsigned c = (is64 ? t[2 * j] : t[j]) & 127u;
        int idx = atomicAdd(&base[c], 1);
        clist[idx] = (unsigned short)j;
    }
}

// ---- per-class membership words: cm2[c*256+t] bit (q*8+e) = (tgb[q*2048+t*8+e]==c) ----
__global__ void class_masks(const unsigned char* __restrict__ tgb,
                            unsigned int* __restrict__ cm2) {
    const int c = blockIdx.x, t = threadIdx.x;
    unsigned w = 0;
#pragma unroll
    for (int q = 0; q < 4; ++q) {
        const unsigned char* base = tgb + q * 2048 + t * 8;
        unsigned b = 0;
#pragma unroll
        for (int e = 0; e < 8; ++e)
            b |= ((unsigned)(base[e] == c)) << e;
        w |= b << (8 * q);
    }
    cm2[c * 256 + t] = w;
}

// ---- L2 normalize rows, emit OCP e4m3 fp8 ----
__global__ __launch_bounds__(256) void normalize_k(const float* __restrict__ x,
                                                   unsigned char* __restrict__ nf8) {
    const int wid = threadIdx.x >> 6, lane = threadIdx.x & 63;
    const size_t row = (size_t)blockIdx.x * 4 + wid;
    const float4* xr = (const float4*)(x + row * C_DIM) + lane * 2;
    float4 a = xr[0], b = xr[1];
    float ss = a.x * a.x + a.y * a.y + a.z * a.z + a.w * a.w +
               b.x * b.x + b.y * b.y + b.z * b.z + b.w * b.w;
#pragma unroll
    for (int m = 1; m < 64; m <<= 1) ss += __shfl_xor(ss, m);
    float sc = 1.0f / fmaxf(sqrtf(ss), 1e-12f);
    int w0 = __builtin_amdgcn_cvt_pk_fp8_f32(a.x * sc, a.y * sc, 0, false);
    w0 = __builtin_amdgcn_cvt_pk_fp8_f32(a.z * sc, a.w * sc, w0, true);
    int w1 = __builtin_amdgcn_cvt_pk_fp8_f32(b.x * sc, b.y * sc, 0, false);
    w1 = __builtin_amdgcn_cvt_pk_fp8_f32(b.z * sc, b.w * sc, w1, true);
    int2 o2; o2.x = w0; o2.y = w1;
    *(int2*)(nf8 + row * C_DIM + lane * 8) = o2;
}

// ---- sim keys = negkey(bf16(nf8 @ nf8^T)), fp8 MFMA, 128x128 tiles, BK=128 ----
// staging: rows of 128 B, XOR swizzle over 8 16-B granules (colblock ^= r&7):
// fragment b64 reads land 2 lanes/position -> conflict-free (m136).
__global__ __launch_bounds__(256) void gemm_sim(const unsigned char* __restrict__ nf8,
                                                unsigned short* __restrict__ simk,
                                                int rowBase, int symmetric) {
    __shared__ __align__(16) unsigned char smemB[34816];   // As8|Bs8 (32KB); Cs aliases
    unsigned char* As8 = smemB;
    unsigned char* Bs8 = smemB + 16384;
    int tI, tJ;
    if (symmetric) {
        const int idp = (NTRI - 1) - (int)blockIdx.x;   // row-major triangle order
        int u = (int)((sqrtf(8.0f * (float)idp + 1.0f) - 1.0f) * 0.5f);
        while (u * (u + 1) / 2 > idp) --u;
        while ((u + 1) * (u + 2) / 2 <= idp) ++u;
        const int v = idp - u * (u + 1) / 2;
        tI = (NT - 1) - u;
        tJ = (NT - 1) - v;
    } else {
        tI = blockIdx.y; tJ = blockIdx.x;
    }
    const int tid = threadIdx.x;
    const int wid = tid >> 6, lane = tid & 63;
    const int wm = wid >> 1, wn = wid & 1;
    const int gr = rowBase + tI * 128;
    const int gc = tJ * 128;
    f32x4 zero = {0.f, 0.f, 0.f, 0.f};
    f32x4 acc[4][4];
#pragma unroll
    for (int m = 0; m < 4; ++m)
#pragma unroll
        for (int n = 0; n < 4; ++n) acc[m][n] = zero;

    const int lr = lane >> 3, lcb = lane & 7;           // chunk = 8 rows x 128 B

    for (int k0 = 0; k0 < C_DIM; k0 += 128) {           // 4 K-steps of 128 fp8 elems
#pragma unroll
        for (int i = 0; i < 4; ++i) {
            const int chunk = wid * 4 + i;              // 0..15, wave-uniform
            const int r = chunk * 8 + lr;
            const int sc = (lcb ^ (r & 7)) << 4;        // inverse-swizzled source col-block
            gl_lds16b(nf8 + (size_t)(gr + r) * C_DIM + k0 + sc, As8 + chunk * 1024);
            gl_lds16b(nf8 + (size_t)(gc + r) * C_DIM + k0 + sc, Bs8 + chunk * 1024);
        }
        __syncthreads();
#pragma unroll
        for (int kk = 0; kk < 4; ++kk) {
            const int krow = kk * 32 + (lane >> 4) * 8; // byte offset of 8-elem k-chunk
            long a[4], b[4];
#pragma unroll
            for (int m = 0; m < 4; ++m) {
                const int R = wm * 64 + m * 16 + (lane & 15);
                a[m] = *(const long*)&As8[R * 128 + (krow ^ ((R & 7) << 4))];
            }
#pragma unroll
            for (int n = 0; n < 4; ++n) {
                const int R = wn * 64 + n * 16 + (lane & 15);
                b[n] = *(const long*)&Bs8[R * 128 + (krow ^ ((R & 7) << 4))];
            }
#pragma unroll
            for (int m = 0; m < 4; ++m)
#pragma unroll
                for (int n = 0; n < 4; ++n)
                    acc[m][n] = __builtin_amdgcn_mfma_f32_16x16x32_fp8_fp8(a[m], b[n], acc[m][n], 0, 0, 0);
        }
        __syncthreads();
    }

    // pre-pack keys once; C/D layout: col=lane&15, row=(lane>>4)*4+j
    unsigned short kk4[4][4][4];
#pragma unroll
    for (int m = 0; m < 4; ++m)
#pragma unroll
        for (int n = 0; n < 4; ++n)
#pragma unroll
            for (int j = 0; j < 4; ++j)
                kk4[m][n][j] = (unsigned short)negkey(f2bf(acc[m][n][j]));

    unsigned short* Cs = (unsigned short*)smemB;         // 128*136 shorts = 34816 B
    const int fc = (lane & 15);
    const int fr = (lane >> 4) << 2;

    // ---- direct (row-major) write via row-major bounce ----
#pragma unroll
    for (int m = 0; m < 4; ++m)
#pragma unroll
        for (int n = 0; n < 4; ++n) {
            const int c = wn * 64 + n * 16 + fc;
            const int r0 = wm * 64 + m * 16 + fr;
#pragma unroll
            for (int j = 0; j < 4; ++j)
                Cs[(r0 + j) * 136 + c] = kk4[m][n][j];
        }
    __syncthreads();
#pragma unroll
    for (int k = 0; k < 8; ++k) {
        const int lin = tid + k * 256;
        const int r = lin >> 4;
        const int c0 = (lin & 15) * 8;
        int4 v = *(const int4*)&Cs[r * 136 + c0];
        *(int4*)&simk[(size_t)(gr - rowBase + r) * B_N + gc + c0] = v;
    }

    if (symmetric && tJ > tI) {
        // ---- transposed write via col-major bounce ----
        __syncthreads();
#pragma unroll
        for (int m = 0; m < 4; ++m)
#pragma unroll
            for (int n = 0; n < 4; ++n) {
                const int c = wn * 64 + n * 16 + fc;
                const int r0 = wm * 64 + m * 16 + fr;
                ushort4 pk;
                pk.x = kk4[m][n][0]; pk.y = kk4[m][n][1];
                pk.z = kk4[m][n][2]; pk.w = kk4[m][n][3];
                *(ushort4*)&Cs[c * 136 + r0] = pk;
            }
        __syncthreads();
#pragma unroll
        for (int k = 0; k < 8; ++k) {
            const int lin = tid + k * 256;
            const int c = lin >> 4;
            const int r0 = (lin & 15) * 8;
            int4 v = *(const int4*)&Cs[c * 136 + r0];
            *(int4*)&simk[(size_t)(gc + c) * B_N + gr + r0] = v;
        }
    }
}

// ---- block-per-row selection + loss: candidate compaction above TGKEY, exact bisect ----
__global__ __launch_bounds__(256) void select_loss(const unsigned short* __restrict__ simk,
                                                   const unsigned char* __restrict__ tgb,
                                                   const unsigned int* __restrict__ cm2,
                                                   const unsigned short* __restrict__ clist,
                                                   const int* __restrict__ off,
                                                   float* __restrict__ out, int rowBase) {
    __shared__ int nlist[256];
    __shared__ float s_partial[4];
    __shared__ int nln, s_cnt;

    const int tid = threadIdx.x;
    const int wid = tid >> 6, lane = tid & 63;
    const int row = rowBase + blockIdx.x;
    const unsigned short* srow = simk + (size_t)blockIdx.x * B_N;
    const int ti = tgb[row];
    const int o0 = off[ti], o1 = off[ti + 1];

    // load 32 keys, mask same-class halves to 0 (key 0 < TGKEY: never a candidate)
    int4 A[4];
    const unsigned m = cm2[ti * 256 + tid];
#pragma unroll
    for (int q = 0; q < 4; ++q) {
        A[q] = *(const int4*)(srow + q * 2048 + tid * 8);
#pragma unroll
        for (int d = 0; d < 4; ++d) {
            unsigned two = (m >> (q * 8 + d * 2)) & 3u;
            unsigned kill = ((two & 1u) * 0xFFFFu) | (((two >> 1) & 1u) * 0xFFFF0000u);
            int v = (d == 0 ? A[q].x : d == 1 ? A[q].y : d == 2 ? A[q].z : A[q].w);
            v = (int)((unsigned)v & ~kill);
            if (d == 0) A[q].x = v; else if (d == 1) A[q].y = v;
            else if (d == 2) A[q].z = v; else A[q].w = v;
        }
    }
    if (tid == 0) { nln = 0; s_cnt = 0; }
    __syncthreads();                                             // B1

#define ELEM_LOOP(BODY)                                                          \
    _Pragma("unroll")                                                            \
    for (int q = 0; q < 4; ++q) {                                                \
        _Pragma("unroll")                                                        \
        for (int d = 0; d < 4; ++d) {                                            \
            unsigned w32 = (unsigned)(d == 0 ? A[q].x : d == 1 ? A[q].y          \
                                    : d == 2 ? A[q].z : A[q].w);                 \
            _Pragma("unroll")                                                    \
            for (int h2 = 0; h2 < 2; ++h2) {                                     \
                unsigned key = h2 ? (w32 >> 16) : (w32 & 0xFFFFu);               \
                BODY                                                             \
            }                                                                    \
        }                                                                        \
    }

    // single scan: compact candidates above the conservative pre-threshold
    ELEM_LOOP(
        if (key > TGKEY) { int p = atomicAdd(&nln, 1); if (p < 256) nlist[p] = (int)key; }
    )
    __syncthreads();                                             // B2
    const int NC = nln;

    unsigned thr;
    int kremf;
    float S;

    if (NC >= 64 && NC <= 256) {
        // -------- fast path: wave0 solo; waves 1-3 exit now --------
        if (wid != 0) return;
        unsigned pk[8];
#pragma unroll
        for (int s2 = 0; s2 < 8; ++s2) {
            int idx = o0 + lane + s2 * 64;
            pk[s2] = (idx < o1)
                ? ((((unsigned)srow[clist[idx]]) << 9) | ((unsigned)lane << 3) | (unsigned)s2)
                : 0xFFFFFFFFu;
        }
        int4 cw = *(const int4*)&nlist[lane * 4];
        unsigned cand[4] = {(unsigned)cw.x, (unsigned)cw.y, (unsigned)cw.z, (unsigned)cw.w};
#pragma unroll
        for (int j = 0; j < 4; ++j)
            if (lane * 4 + j >= NC) cand[j] = 0;
        unsigned cur = 0;
#pragma unroll
        for (int bit = 15; bit >= 0; --bit) {
            unsigned trial = cur | (1u << bit);
            int c = (cand[0] >= trial) + (cand[1] >= trial) +
                    (cand[2] >= trial) + (cand[3] >= trial);
#pragma unroll
            for (int o = 1; o < 64; o <<= 1) c += __shfl_xor(c, o);
            if (c >= 64) cur = trial;
        }
        int r = (cand[0] > cur) + (cand[1] > cur) + (cand[2] > cur) + (cand[3] > cur);
#pragma unroll
        for (int o = 1; o < 64; o <<= 1) r += __shfl_xor(r, o);
        kremf = 64 - r;
        float f = 0.f;
#pragma unroll
        for (int j = 0; j < 4; ++j)
            if (cand[j] > cur) f += __expf(2.0f * bf2f(unkey(cand[j])));
#pragma unroll
        for (int o = 1; o < 64; o <<= 1) f += __shfl_xor(f, o);
        S = f;
        thr = cur;

        S += (float)kremf * __expf(2.0f * bf2f(unkey(thr)));
        float acc = 0.f;
#pragma unroll
        for (int rd = 0; rd < 8; ++rd) {
            unsigned best = pk[0];
#pragma unroll
            for (int s2 = 1; s2 < 8; ++s2) best = best < pk[s2] ? best : pk[s2];
#pragma unroll
            for (int o = 1; o < 64; o <<= 1) {
                unsigned v = (unsigned)__shfl_xor((int)best, o);
                best = best < v ? best : v;
            }
            if (best != 0xFFFFFFFFu) {
                if (lane == (int)((best >> 3) & 63u)) pk[best & 7u] = 0xFFFFFFFFu;
                if (lane == 0) {
                    float p = bf2f(unkey(best >> 9));
                    acc += logf(__expf(2.0f * p) + S) - 2.0f * p;
                }
            }
        }
        if (lane == 0) out[row] = acc * 0.125f;
    } else {
        // -------- exact fallback (distribution-independent): block-wide bisection --------
        unsigned cur = 0;
        for (int bit = 15; bit >= 0; --bit) {
            unsigned trial = cur | (1u << bit);
            int c = 0;
            ELEM_LOOP( c += (key >= trial) ? 1 : 0; )
#pragma unroll
            for (int o = 1; o < 64; o <<= 1) c += __shfl_xor(c, o);
            if (lane == 0) atomicAdd(&s_cnt, c);
            __syncthreads();
            int tot = s_cnt;
            __syncthreads();
            if (tid == 0) s_cnt = 0;
            __syncthreads();
            if (tot >= 64) cur = trial;
        }
        {
            int c = 0;
            ELEM_LOOP( c += (key > cur) ? 1 : 0; )
#pragma unroll
            for (int o = 1; o < 64; o <<= 1) c += __shfl_xor(c, o);
            if (lane == 0) atomicAdd(&s_cnt, c);
            __syncthreads();
        }
        const int r = s_cnt;
        kremf = 64 - r;
        {
            float f = 0.f;
            ELEM_LOOP( if (key > cur) f += __expf(2.0f * bf2f(unkey(key))); )
#pragma unroll
            for (int o = 1; o < 64; o <<= 1) f += __shfl_xor(f, o);
            if (lane == 0) s_partial[wid] = f;
            __syncthreads();
        }
        if (wid != 0) return;
        S = s_partial[0] + s_partial[1] + s_partial[2] + s_partial[3];
        thr = cur;

        unsigned pk[8];
#pragma unroll
        for (int s2 = 0; s2 < 8; ++s2) {
            int idx = o0 + lane + s2 * 64;
            pk[s2] = (idx < o1)
                ? ((((unsigned)srow[clist[idx]]) << 9) | ((unsigned)lane << 3) | (unsigned)s2)
                : 0xFFFFFFFFu;
        }
        S += (float)kremf * __expf(2.0f * bf2f(unkey(thr)));
        float acc = 0.f;
#pragma unroll
        for (int rd = 0; rd < 8; ++rd) {
            unsigned best = pk[0];
#pragma unroll
            for (int s2 = 1; s2 < 8; ++s2) best = best < pk[s2] ? best : pk[s2];
#pragma unroll
            for (int o = 1; o < 64; o <<= 1) {
                unsigned v = (unsigned)__shfl_xor((int)best, o);
                best = best < v ? best : v;
            }
            if (best != 0xFFFFFFFFu) {
                if (lane == (int)((best >> 3) & 63u)) pk[best & 7u] = 0xFFFFFFFFu;
                if (lane == 0) {
                    float p = bf2f(unkey(best >> 9));
                    acc += logf(__expf(2.0f * p) + S) - 2.0f * p;
                }
            }
        }
        if (lane == 0) out[row] = acc * 0.125f;
    }
#undef ELEM_LOOP
}

extern "C" void kernel_launch(void* const* d_in, const int* in_sizes, int n_in,
                              void* d_out, int out_size, void* d_ws, size_t ws_size,
                              hipStream_t stream) {
    const float* newf = (const float*)d_in[1];
    const unsigned int* tgtw = (const unsigned int*)d_in[2];
    float* out = (float*)d_out;
    char* ws = (char*)d_ws;
    unsigned char* tgb = (unsigned char*)ws;                          // 8 KB
    unsigned int* cm2 = (unsigned int*)(ws + 8192);                   // 100 KB
    int* off = (int*)(ws + 110592);                                   // 1 KB (129 ints)
    unsigned short* clist = (unsigned short*)(ws + 111616);           // 16 KB
    unsigned char* nf8 = (unsigned char*)(ws + 131072);               // 4 MB fp8 (aligned)
    unsigned short* simk = (unsigned short*)(ws + 131072 + ((size_t)4 << 20));

    size_t fixed = 131072 + ((size_t)4 << 20);
    size_t avail = (ws_size > fixed) ? (ws_size - fixed) : 0;
    long maxRows = (long)(avail / ((size_t)B_N * 2));
    int chunk = (int)((maxRows / 128) * 128);
    if (chunk < 128) chunk = 128;
    if (chunk > B_N) chunk = B_N;

    hipLaunchKernelGGL(prep_all, dim3(1), dim3(256), 0, stream, tgtw, tgb, clist, off);
    hipLaunchKernelGGL(class_masks, dim3(100), dim3(256), 0, stream, tgb, cm2);
    hipLaunchKernelGGL(normalize_k, dim3(B_N / 4), dim3(256), 0, stream, newf, nf8);
    if (chunk == B_N) {
        hipLaunchKernelGGL(gemm_sim, dim3(NTRI), dim3(256), 0, stream, nf8, simk, 0, 1);
        hipLaunchKernelGGL(select_loss, dim3(B_N), dim3(256), 0, stream,
                           simk, tgb, cm2, clist, off, out, 0);
    } else {
        for (int r0 = 0; r0 < B_N; r0 += chunk) {
            int rows = (B_N - r0 < chunk) ? (B_N - r0) : chunk;
            hipLaunchKernelGGL(gemm_sim, dim3(64, rows / 128), dim3(256), 0, stream,
                               nf8, simk, r0, 0);
            hipLaunchKernelGGL(select_loss, dim3(rows), dim3(256), 0, stream,
                               simk, tgb, cm2, clist, off, out, r0);
        }
    }
}